// Round 1
// baseline (2127.028 us; speedup 1.0000x reference)
//
#include <hip/hip_runtime.h>
#include <stdint.h>

// ---- Problem constants ----
#define Hh   16
#define HD   256
#define Dm   4096
#define N3   12288
#define Ss   2048
#define Bb   2
#define MT   (Bb*Ss)      // 4096 tokens
#define ROTD 64

typedef __attribute__((ext_vector_type(8)))  __bf16 bf16x8;
typedef __attribute__((ext_vector_type(4)))  float  f32x4;
typedef __attribute__((ext_vector_type(16))) float  f32x16;

__device__ __forceinline__ uint16_t f2bf(float f) {
    uint32_t u = __builtin_bit_cast(uint32_t, f);
    return (uint16_t)((u + 0x7FFFu + ((u >> 16) & 1u)) >> 16);   // RNE
}
__device__ __forceinline__ uint32_t pkbf(float lo, float hi) {
    return (uint32_t)f2bf(lo) | ((uint32_t)f2bf(hi) << 16);
}

#define GLL16(gp, lp) \
    __builtin_amdgcn_global_load_lds((const __attribute__((address_space(1))) void*)(gp), \
                                     (__attribute__((address_space(3))) void*)(lp), 16, 0, 0)

// ---------------- convert fp32 -> bf16 (flat) ----------------
__global__ void cvt_kernel(const float* __restrict__ src, uint16_t* __restrict__ dst, int n4) {
    int i = blockIdx.x * blockDim.x + threadIdx.x;
    int stride = gridDim.x * blockDim.x;
    for (; i < n4; i += stride) {
        float4 v = ((const float4*)src)[i];
        ushort4 o; o.x = f2bf(v.x); o.y = f2bf(v.y); o.z = f2bf(v.z); o.w = f2bf(v.w);
        ((ushort4*)dst)[i] = o;
    }
}

// ---------------- transpose + convert: src (R x C) f32 -> dst (C x R) bf16 ----------------
__global__ void tcvt_kernel(const float* __restrict__ src, uint16_t* __restrict__ dst, int R, int C) {
    __shared__ float ls[32][33];
    int c0 = blockIdx.x * 32, r0 = blockIdx.y * 32;
    int t = threadIdx.x;
    int rl = t >> 3, cl = (t & 7) * 4;
    float4 v = *(const float4*)(src + (size_t)(r0 + rl) * C + c0 + cl);
    ls[rl][cl + 0] = v.x; ls[rl][cl + 1] = v.y; ls[rl][cl + 2] = v.z; ls[rl][cl + 3] = v.w;
    __syncthreads();
    int cc = t >> 3, r4 = (t & 7) * 4;
    ushort4 o;
    o.x = f2bf(ls[r4 + 0][cc]); o.y = f2bf(ls[r4 + 1][cc]);
    o.z = f2bf(ls[r4 + 2][cc]); o.w = f2bf(ls[r4 + 3][cc]);
    *(ushort4*)(dst + (size_t)(c0 + cc) * R + r0 + r4) = o;
}

// ---------------- V (tok-major, head-strided) -> V^T per (b,h): (B,H,HD,S) ----------------
__global__ void vtrans_kernel(const uint16_t* __restrict__ v, uint16_t* __restrict__ vt) {
    __shared__ uint16_t ls[32][40];
    int s0 = blockIdx.x * 32, d0 = blockIdx.y * 32;
    int bh = blockIdx.z; int b = bh >> 4, h = bh & 15;
    const uint16_t* src = v + (size_t)(b * Ss) * Dm + h * HD;
    uint16_t* dst = vt + (size_t)bh * HD * Ss;
    int t = threadIdx.x;
    int sl = t >> 3, dl = (t & 7) * 4;
    ushort4 x = *(const ushort4*)(src + (size_t)(s0 + sl) * Dm + d0 + dl);
    ls[sl][dl + 0] = x.x; ls[sl][dl + 1] = x.y; ls[sl][dl + 2] = x.z; ls[sl][dl + 3] = x.w;
    __syncthreads();
    int dd = t >> 3, s4 = (t & 7) * 4;
    ushort4 o;
    o.x = ls[s4 + 0][dd]; o.y = ls[s4 + 1][dd]; o.z = ls[s4 + 2][dd]; o.w = ls[s4 + 3][dd];
    *(ushort4*)(dst + (size_t)(d0 + dd) * Ss + s0 + s4) = o;
}

// ---------------- 128x128 bf16 MFMA GEMM, BK=32 (m97 structure) ----------------
// A: (M x 4096) bf16 row-major.  BT: (N x 4096) bf16 row-major (= B transposed).
// MODE 0: C fp32 -> outc (ld 4096).  MODE 1: qkv epilogue (RoPE on q/k, split to q/k/v bf16).
template <int MODE>
__global__ __launch_bounds__(256) void gemm_bt(
    const uint16_t* __restrict__ A, const uint16_t* __restrict__ BT,
    const int* __restrict__ posids,
    uint16_t* __restrict__ qb, uint16_t* __restrict__ kb, uint16_t* __restrict__ vb,
    float* __restrict__ outc)
{
    __shared__ uint16_t As[128 * 32];
    __shared__ uint16_t Bs[128 * 32];
    const int K = 4096;
    int t = threadIdx.x;
    int w = t >> 6, l = t & 63;
    int wr = w >> 1, wc = w & 1;
    int l15 = l & 15, l4 = l >> 4;
    int m0 = blockIdx.y * 128, n0 = blockIdx.x * 128;

    f32x4 acc[4][4];
#pragma unroll
    for (int i = 0; i < 4; i++)
#pragma unroll
        for (int j = 0; j < 4; j++)
#pragma unroll
            for (int r = 0; r < 4; r++) acc[i][j][r] = 0.f;

    int rowA0 = t >> 2, koff0 = (t & 3) * 8;
    for (int k0 = 0; k0 < K; k0 += 32) {
        GLL16(A  + (size_t)(m0 + rowA0)      * K + k0 + koff0, As + (size_t)(w * 64) * 8);
        GLL16(A  + (size_t)(m0 + rowA0 + 64) * K + k0 + koff0, As + (size_t)(256 + w * 64) * 8);
        GLL16(BT + (size_t)(n0 + rowA0)      * K + k0 + koff0, Bs + (size_t)(w * 64) * 8);
        GLL16(BT + (size_t)(n0 + rowA0 + 64) * K + k0 + koff0, Bs + (size_t)(256 + w * 64) * 8);
        __syncthreads();
        bf16x8 af[4], bfr[4];
#pragma unroll
        for (int mm = 0; mm < 4; mm++)
            af[mm] = *(const bf16x8*)(As + (size_t)(wr * 64 + mm * 16 + l15) * 32 + l4 * 8);
#pragma unroll
        for (int nn = 0; nn < 4; nn++)
            bfr[nn] = *(const bf16x8*)(Bs + (size_t)(wc * 64 + nn * 16 + l15) * 32 + l4 * 8);
#pragma unroll
        for (int mm = 0; mm < 4; mm++)
#pragma unroll
            for (int nn = 0; nn < 4; nn++)
                acc[mm][nn] = __builtin_amdgcn_mfma_f32_16x16x32_bf16(af[mm], bfr[nn], acc[mm][nn], 0, 0, 0);
        __syncthreads();
    }

    // Epilogue. C layout: col = l&15, row = (l>>4)*4 + r (verified m89).
#pragma unroll
    for (int mm = 0; mm < 4; mm++) {
#pragma unroll
        for (int nn = 0; nn < 4; nn++) {
            int col = n0 + wc * 64 + nn * 16 + l15;
            if (MODE == 0) {
#pragma unroll
                for (int r = 0; r < 4; r++) {
                    int row = m0 + wr * 64 + mm * 16 + l4 * 4 + r;
                    outc[(size_t)row * Dm + col] = acc[mm][nn][r];
                }
            } else {
                int sec = col >> 12;            // 0=q 1=k 2=v
                int jj  = col & 4095;
                int d   = jj & 255;
                int dbase = (n0 + wc * 64 + nn * 16) & 255;   // uniform per fragment
                bool rope = (sec < 2) && (dbase < ROTD);
                uint16_t* dst = (sec == 0) ? qb : ((sec == 1) ? kb : vb);
#pragma unroll
                for (int r = 0; r < 4; r++) {
                    int row = m0 + wr * 64 + mm * 16 + l4 * 4 + r;
                    float v = acc[mm][nn][r];
                    if (rope) {
                        float other = __shfl_xor(v, 1);
                        int pos = posids[row];
                        float invf = expf(-(float)(d & ~1) * 0.14391156514261228f); // ln(1e4)/64
                        float fr = (float)pos * invf;
                        float sn, cs; sincosf(fr, &sn, &cs);
                        v = (l & 1) ? (v * cs + other * sn) : (v * cs - other * sn);
                    }
                    dst[(size_t)row * Dm + jj] = f2bf(v);
                }
            }
        }
    }
}

// ---------------- flash attention: swapped QK^T (S^T = K Q^T), barrier-free ----------------
// Block: 256 thr = 4 waves. wave w: qh=w>>1 (32-q group), dh=w&1 (128-d half).
// Each wave: full online softmax for its 32 q rows, PV into its d-half. QK duplicated per dh.
__global__ __launch_bounds__(256) void flash_kernel(
    const uint16_t* __restrict__ qb, const uint16_t* __restrict__ kb,
    const uint16_t* __restrict__ vt, uint16_t* __restrict__ attn)
{
    __shared__ uint16_t ls[4][32 * 136];  // per-wave O^T transpose staging
    int t = threadIdx.x;
    int w = t >> 6, l = t & 63;
    int qh = w >> 1, dh = w & 1;
    int l31 = l & 31, hi = l >> 5;
    int bh = blockIdx.y; int b = bh >> 4, h = bh & 15;
    int q0w = blockIdx.x * 64 + qh * 32;
    int q = q0w + l31;

    const uint16_t* qrow  = qb + (size_t)(b * Ss + q) * Dm + h * HD;
    const uint16_t* kbase = kb + (size_t)(b * Ss) * Dm + h * HD;
    const uint16_t* vbase = vt + ((size_t)bh * HD + dh * 128) * Ss;

    bf16x8 qf[16];
#pragma unroll
    for (int kk = 0; kk < 16; kk++) qf[kk] = *(const bf16x8*)(qrow + kk * 16 + hi * 8);

    f32x16 oacc[4];
#pragma unroll
    for (int dn = 0; dn < 4; dn++)
#pragma unroll
        for (int r = 0; r < 16; r++) oacc[dn][r] = 0.f;

    float m_run = -1e30f, l_run = 0.f;
    const float scale = 0.0625f;
    int nt = blockIdx.x * 2 + qh + 1;

    for (int ti = 0; ti < nt; ti++) {
        int k0 = ti * 32;
        const uint16_t* krow = kbase + (size_t)(k0 + l31) * Dm;
        f32x16 s0a, s1a;
#pragma unroll
        for (int r = 0; r < 16; r++) { s0a[r] = 0.f; s1a[r] = 0.f; }
#pragma unroll
        for (int kk = 0; kk < 16; kk += 2) {
            bf16x8 kf0 = *(const bf16x8*)(krow + kk * 16 + hi * 8);
            bf16x8 kf1 = *(const bf16x8*)(krow + (kk + 1) * 16 + hi * 8);
            s0a = __builtin_amdgcn_mfma_f32_32x32x16_bf16(kf0, qf[kk],     s0a, 0, 0, 0);
            s1a = __builtin_amdgcn_mfma_f32_32x32x16_bf16(kf1, qf[kk + 1], s1a, 0, 0, 0);
        }
        float p[16]; float mt = -1e30f;
#pragma unroll
        for (int r = 0; r < 16; r++) {
            int kl = (r & 3) + 8 * (r >> 2) + 4 * hi;
            float s = (s0a[r] + s1a[r]) * scale;
            if (k0 + kl > q) s = -1e30f;
            p[r] = s; mt = fmaxf(mt, s);
        }
        mt = fmaxf(mt, __shfl_xor(mt, 32));
        float m_new = fmaxf(m_run, mt);
        float lt = 0.f;
#pragma unroll
        for (int r = 0; r < 16; r++) { p[r] = expf(p[r] - m_new); lt += p[r]; }
        lt += __shfl_xor(lt, 32);
        float alpha = expf(m_run - m_new);
        m_run = m_new; l_run = l_run * alpha + lt;
#pragma unroll
        for (int dn = 0; dn < 4; dn++)
#pragma unroll
            for (int r = 0; r < 16; r++) oacc[dn][r] = oacc[dn][r] * alpha;

        // P^T bf16 B-fragments via pack + lane^32 swap (T12 pattern)
        uint32_t wd[8], sw[8];
#pragma unroll
        for (int g = 0; g < 4; g++) {
            wd[2 * g + 0] = pkbf(p[4 * g + 0], p[4 * g + 1]);
            wd[2 * g + 1] = pkbf(p[4 * g + 2], p[4 * g + 3]);
        }
#pragma unroll
        for (int j = 0; j < 8; j++) sw[j] = (uint32_t)__shfl_xor((int)wd[j], 32);
        bf16x8 pf[2];
#pragma unroll
        for (int s2 = 0; s2 < 2; s2++) {
            int g = 2 * s2 + hi;
            int4 ww;
            ww.x = (int)(hi ? sw[2 * g]     : wd[2 * g]);
            ww.y = (int)(hi ? sw[2 * g + 1] : wd[2 * g + 1]);
            ww.z = (int)(hi ? wd[2 * g]     : sw[2 * g]);
            ww.w = (int)(hi ? wd[2 * g + 1] : sw[2 * g + 1]);
            pf[s2] = __builtin_bit_cast(bf16x8, ww);
        }
        // PV: O^T += V^T * P^T
#pragma unroll
        for (int dn = 0; dn < 4; dn++) {
            const uint16_t* vrow = vbase + (size_t)(dn * 32 + l31) * Ss + k0 + hi * 8;
#pragma unroll
            for (int s2 = 0; s2 < 2; s2++) {
                bf16x8 vf = *(const bf16x8*)(vrow + s2 * 16);
                oacc[dn] = __builtin_amdgcn_mfma_f32_32x32x16_bf16(vf, pf[s2], oacc[dn], 0, 0, 0);
            }
        }
    }

    float invl = 1.0f / l_run;
    uint16_t* lw = &ls[w][0];
#pragma unroll
    for (int dn = 0; dn < 4; dn++)
#pragma unroll
        for (int g = 0; g < 4; g++) {
            int dloc = dn * 32 + 8 * g + 4 * hi;
            uint32_t w0 = pkbf(oacc[dn][4 * g + 0] * invl, oacc[dn][4 * g + 1] * invl);
            uint32_t w1 = pkbf(oacc[dn][4 * g + 2] * invl, oacc[dn][4 * g + 3] * invl);
            *(uint32_t*)(lw + l31 * 136 + dloc)     = w0;
            *(uint32_t*)(lw + l31 * 136 + dloc + 2) = w1;
        }
    // same-wave LDS RAW; compiler inserts lgkmcnt wait
#pragma unroll
    for (int i = 0; i < 8; i++) {
        int c = l + 64 * i;
        int qr = c >> 4, doff = (c & 15) * 8;
        int4 vdat = *(const int4*)(lw + qr * 136 + doff);
        int qg = blockIdx.x * 64 + qh * 32 + qr;
        *(int4*)(attn + (size_t)(b * Ss + qg) * Dm + h * HD + dh * 128 + doff) = vdat;
    }
}

// ---------------- launch ----------------
extern "C" void kernel_launch(void* const* d_in, const int* in_sizes, int n_in,
                              void* d_out, int out_size, void* d_ws, size_t ws_size,
                              hipStream_t stream) {
    const int*   posids = (const int*)d_in[0];
    const float* hs     = (const float*)d_in[1];
    const float* wqkv   = (const float*)d_in[2];
    const float* wout   = (const float*)d_in[3];
    float* out = (float*)d_out;

    // ws layout (bf16 buffers), total 301,989,888 B
    if (ws_size < 301989888ull) return;  // visible failure rather than OOB corruption
    uint8_t* wsb = (uint8_t*)d_ws;
    uint16_t* hsb  = (uint16_t*)(wsb);                  // 33.55 MB  hidden bf16
    uint16_t* wqt  = (uint16_t*)(wsb + 33554432);       // 100.66 MB w_qkv^T bf16
    uint16_t* wot  = (uint16_t*)(wsb + 134217728);      // 33.55 MB  w_out^T bf16
    uint16_t* qbuf = (uint16_t*)(wsb + 167772160);
    uint16_t* kbuf = (uint16_t*)(wsb + 201326592);
    uint16_t* vbuf = (uint16_t*)(wsb + 234881024);
    uint16_t* vtb  = (uint16_t*)(wsb + 268435456);
    uint16_t* attnb = hsb;  // alias: hsb dead after qkv GEMM

    cvt_kernel<<<4096, 256, 0, stream>>>(hs, hsb, MT * Dm / 4);
    tcvt_kernel<<<dim3(N3 / 32, Dm / 32), 256, 0, stream>>>(wqkv, wqt, Dm, N3);
    tcvt_kernel<<<dim3(Dm / 32, Dm / 32), 256, 0, stream>>>(wout, wot, Dm, Dm);
    gemm_bt<1><<<dim3(N3 / 128, MT / 128), 256, 0, stream>>>(hsb, wqt, posids, qbuf, kbuf, vbuf, nullptr);
    vtrans_kernel<<<dim3(Ss / 32, HD / 32, Bb * Hh), 256, 0, stream>>>(vbuf, vtb);
    flash_kernel<<<dim3(Ss / 64, Bb * Hh), 256, 0, stream>>>(qbuf, kbuf, vtb, attnb);
    gemm_bt<0><<<dim3(Dm / 128, MT / 128), 256, 0, stream>>>(attnb, wot, nullptr, nullptr, nullptr, nullptr, out);
}